// Round 5
// baseline (181.413 us; speedup 1.0000x reference)
//
#include <hip/hip_runtime.h>

// SlidingWindowAttention: B=1, S=4096, D=1024, H=16, d=64, WIN=512 (256 back / 255 fwd)
// Inputs/outputs FP32 storage (values bf16-rounded by harness).
//
// Pipeline:
//   0) cvt_f32_bf16 x3 : x, Wqkv, Wout -> bf16 (ws)
//   1) gemm_qkv        : qkv GEMM (64x128 tiles, 1536 blocks = 6/CU for
//                        latency hiding), scatters Q->Qb, K->Kp(pad), V->Vb
//   2) repack_v        : Vb -> VTp padded (h,d,key+256); zeroes Kp/VTp pads
//   3) swa_fused       : 128 queries/block, 10 key tiles, gll16 staging,
//                        fixed-max softmax -> o (aliases Vb)
//   4) gemm_out        : out = o @ Wout^T + bout (64x64 tiles, 1024 blocks)

typedef __bf16 bf16x8 __attribute__((ext_vector_type(8)));
typedef float f32x4 __attribute__((ext_vector_type(4)));
typedef unsigned short u16;
typedef unsigned int u32;

#define MFMA16(a, b, c) __builtin_amdgcn_mfma_f32_16x16x32_bf16(a, b, c, 0, 0, 0)

__device__ __forceinline__ u16 f2b(float f) {   // RNE f32 -> bf16 bits
  union { float f; u32 u; } x; x.f = f;
  u32 r = x.u + 0x7fffu + ((x.u >> 16) & 1u);
  return (u16)(r >> 16);
}

union U8x16 { int4 v; u16 u[8]; };

// async 16B global -> LDS (dest = wave-uniform base + lane*16, HW-generated)
__device__ __forceinline__ void gll16(const u16* g, u16* l) {
  __builtin_amdgcn_global_load_lds(
      (const __attribute__((address_space(1))) u16*)g,
      (__attribute__((address_space(3))) u16*)l, 16, 0, 0);
}

// ---------------------------------------------------------------------------
__global__ void cvt_f32_bf16(const float* __restrict__ in, u16* __restrict__ out, int n8)
{
  const int i = blockIdx.x * blockDim.x + threadIdx.x;
  if (i >= n8) return;
  const float4 a = ((const float4*)in)[i * 2];
  const float4 b = ((const float4*)in)[i * 2 + 1];
  U8x16 t;
  t.u[0] = f2b(a.x); t.u[1] = f2b(a.y); t.u[2] = f2b(a.z); t.u[3] = f2b(a.w);
  t.u[4] = f2b(b.x); t.u[5] = f2b(b.y); t.u[6] = f2b(b.z); t.u[7] = f2b(b.w);
  ((int4*)out)[i] = t.v;
}

// ---------------------------------------------------------------------------
// QKV GEMM: 64x128 tile (BM=64 -> grid 24x64 = 1536 blocks = 6/CU), BK=32,
// gll16 staging with XOR chunk swizzle (slot s of row r holds global chunk
// s ^ ((r>>1)&3); fragment slot = quad ^ ((c16>>1)&3)) -> conflict-free.
// 2x2 waves, each wave 32x64 output (2x4 MFMA tiles).
// Epilogue scatters: Q (n<1024) -> Qb; K -> Kp (h, key+256, d); V -> Vb.
// ---------------------------------------------------------------------------
__global__ __launch_bounds__(256, 4) void gemm_qkv(
    const u16* __restrict__ A, const u16* __restrict__ B,
    const float* __restrict__ bias,
    u16* __restrict__ Qb, u16* __restrict__ Kp, u16* __restrict__ Vb)
{
  __shared__ u16 As[64 * 32];    // 4 KB
  __shared__ u16 Bs[128 * 32];   // 8 KB

  const int K = 1024;
  const int tid  = threadIdx.x;
  const int lane = tid & 63;
  const int wave = tid >> 6;
  const int quad = lane >> 4;
  const int c16  = lane & 15;
  const int wr   = wave >> 1;            // M half (32 rows)
  const int wc   = wave & 1;             // N half (64 cols)
  const long m0 = (long)blockIdx.y * 64;
  const long n0 = (long)blockIdx.x * 128;

  // staging lane map: lane i -> row base+(i>>2), global chunk (i&3)^((i>>3)&3)
  const int srA   = wave * 16 + (lane >> 2);   // A: 16 rows/wave
  const int srB   = wave * 32 + (lane >> 2);   // B: 32 rows/wave (2 gll16)
  const int schunk = (lane & 3) ^ ((lane >> 3) & 3);
  const u16* gA0 = &A[(m0 + srA) * K + schunk * 8];
  const u16* gB0 = &B[(n0 + srB) * K + schunk * 8];
  const u16* gB1 = &B[(n0 + srB + 16) * K + schunk * 8];
  u16* const lA0 = &As[(wave * 16) * 32];
  u16* const lB0 = &Bs[(wave * 32) * 32];
  u16* const lB1 = &Bs[(wave * 32 + 16) * 32];

  const int cs = (quad ^ ((c16 >> 1) & 3)) * 8;
  const u16* pa[2]; const u16* pb[4];
#pragma unroll
  for (int i = 0; i < 2; ++i) pa[i] = &As[(wr * 32 + i * 16 + c16) * 32 + cs];
#pragma unroll
  for (int j = 0; j < 4; ++j) pb[j] = &Bs[(wc * 64 + j * 16 + c16) * 32 + cs];

  f32x4 acc[2][4];
#pragma unroll
  for (int i = 0; i < 2; ++i)
#pragma unroll
    for (int j = 0; j < 4; ++j)
      acc[i][j] = f32x4{0.f, 0.f, 0.f, 0.f};

  for (int k0 = 0; k0 < K; k0 += 32) {
    __syncthreads();
    gll16(gA0, lA0);
    gll16(gB0, lB0); gll16(gB1, lB1);
    gA0 += 32; gB0 += 32; gB1 += 32;
    __syncthreads();

    bf16x8 af[2], bfr[4];
#pragma unroll
    for (int i = 0; i < 2; ++i) af[i]  = *(const bf16x8*)pa[i];
#pragma unroll
    for (int j = 0; j < 4; ++j) bfr[j] = *(const bf16x8*)pb[j];
#pragma unroll
    for (int i = 0; i < 2; ++i)
#pragma unroll
      for (int j = 0; j < 4; ++j)
        acc[i][j] = MFMA16(af[i], bfr[j], acc[i][j]);
  }

  const int region = (int)(n0 >> 10);      // 0=Q, 1=K, 2=V (block-uniform)
#pragma unroll
  for (int i = 0; i < 2; ++i) {
    const long row0 = m0 + wr * 32 + i * 16 + quad * 4;
#pragma unroll
    for (int j = 0; j < 4; ++j) {
      const long col = n0 + wc * 64 + j * 16 + c16;
      const float bv = bias[col];
#pragma unroll
      for (int r = 0; r < 4; ++r) {
        const u16 v = f2b(acc[i][j][r] + bv);
        const long row = row0 + r;
        if (region == 0) {
          Qb[row * 1024 + col] = v;
        } else if (region == 1) {
          const int n1 = (int)(col - 1024);
          const int h = n1 >> 6, d = n1 & 63;
          Kp[((long)h * 4608 + row + 256) * 64 + d] = v;
        } else {
          Vb[row * 1024 + (col - 2048)] = v;
        }
      }
    }
  }
}

// ---------------------------------------------------------------------------
// Output GEMM: 64x64 tile (grid 16x64 = 1024 blocks = 4/CU), BK=32.
// 2x2 waves, each 32x32 (2x2 MFMA tiles). fp32 out.
// ---------------------------------------------------------------------------
__global__ __launch_bounds__(256, 4) void gemm_out(
    const u16* __restrict__ A, const u16* __restrict__ B,
    const float* __restrict__ bias, float* __restrict__ C)
{
  __shared__ u16 As[64 * 32];    // 4 KB
  __shared__ u16 Bs[64 * 32];    // 4 KB

  const int K = 1024, N = 1024;
  const int tid  = threadIdx.x;
  const int lane = tid & 63;
  const int wave = tid >> 6;
  const int quad = lane >> 4;
  const int c16  = lane & 15;
  const int wr   = wave >> 1;
  const int wc   = wave & 1;
  const long m0 = (long)blockIdx.y * 64;
  const long n0 = (long)blockIdx.x * 64;

  const int srow   = wave * 16 + (lane >> 2);
  const int schunk = (lane & 3) ^ ((lane >> 3) & 3);
  const u16* gA0 = &A[(m0 + srow) * K + schunk * 8];
  const u16* gB0 = &B[(n0 + srow) * K + schunk * 8];
  u16* const lA0 = &As[(wave * 16) * 32];
  u16* const lB0 = &Bs[(wave * 16) * 32];

  const int cs = (quad ^ ((c16 >> 1) & 3)) * 8;
  const u16* pa[2]; const u16* pb[2];
#pragma unroll
  for (int i = 0; i < 2; ++i) {
    pa[i] = &As[(wr * 32 + i * 16 + c16) * 32 + cs];
    pb[i] = &Bs[(wc * 32 + i * 16 + c16) * 32 + cs];
  }

  f32x4 acc[2][2];
#pragma unroll
  for (int i = 0; i < 2; ++i)
#pragma unroll
    for (int j = 0; j < 2; ++j)
      acc[i][j] = f32x4{0.f, 0.f, 0.f, 0.f};

  for (int k0 = 0; k0 < K; k0 += 32) {
    __syncthreads();
    gll16(gA0, lA0);
    gll16(gB0, lB0);
    gA0 += 32; gB0 += 32;
    __syncthreads();

    bf16x8 af[2], bfr[2];
#pragma unroll
    for (int i = 0; i < 2; ++i) af[i]  = *(const bf16x8*)pa[i];
#pragma unroll
    for (int j = 0; j < 2; ++j) bfr[j] = *(const bf16x8*)pb[j];
#pragma unroll
    for (int i = 0; i < 2; ++i)
#pragma unroll
      for (int j = 0; j < 2; ++j)
        acc[i][j] = MFMA16(af[i], bfr[j], acc[i][j]);
  }

#pragma unroll
  for (int i = 0; i < 2; ++i) {
    const long row0 = m0 + wr * 32 + i * 16 + quad * 4;
#pragma unroll
    for (int j = 0; j < 2; ++j) {
      const long col = n0 + wc * 32 + j * 16 + c16;
      const float bv = bias[col];
#pragma unroll
      for (int r = 0; r < 4; ++r)
        C[(row0 + r) * N + col] = acc[i][j][r] + bv;
    }
  }
}

// ---------------------------------------------------------------------------
// V repack: Vb(S,D) -> VTp(h, d, key+256) transposed; zeroes pad tiles of
// both Kp and VTp. Grid (72 padded key tiles, 16 heads), 256 threads.
// Dual-XOR swizzled LDS transpose -> both write and read conflict-free.
// ---------------------------------------------------------------------------
__global__ __launch_bounds__(256, 2) void repack_v(
    const u16* __restrict__ Vb, u16* __restrict__ Kp, u16* __restrict__ VTp)
{
  __shared__ u16 lds[64 * 64];
  const int tile = blockIdx.x;          // padded key tile, 0..71
  const int h    = blockIdx.y;
  const int tid  = threadIdx.x;
  const int kt   = tile * 64 - 256;     // actual key start
  const long vtb = (long)h * 64 * 4608;

  if (kt < 0 || kt >= 4096) {           // pad tile: zero Kp rows + VTp cols
    const int4 z = {0, 0, 0, 0};
    for (int idx = tid; idx < 512; idx += 256) {
      const int r = idx >> 3, c = idx & 7;
      *(int4*)(&Kp[((long)h * 4608 + tile * 64 + r) * 64 + c * 8]) = z;
      *(int4*)(&VTp[vtb + (long)r * 4608 + tile * 64 + c * 8])     = z;
    }
    return;
  }

  for (int idx = tid; idx < 512; idx += 256) {
    const int r = idx >> 3, c = idx & 7;            // key r, d-chunk c
    U8x16 t; t.v = *(const int4*)(&Vb[(long)(kt + r) * 1024 + h * 64 + c * 8]);
#pragma unroll
    for (int j = 0; j < 8; ++j) {
      const int d = c * 8 + j;
      lds[d * 64 + (((r >> 3) ^ ((c + j) & 7)) * 8) + (r & 7)] = t.u[j];
    }
  }
  __syncthreads();
  for (int idx = tid; idx < 512; idx += 256) {
    const int d = idx >> 3, c2 = idx & 7;           // d row, key-chunk c2
    const int sl = (c2 ^ ((d + (d >> 3)) & 7)) * 8;
    const int4 v = *(const int4*)(&lds[d * 64 + sl]);
    *(int4*)(&VTp[vtb + (long)d * 4608 + 256 + kt + c2 * 8]) = v;
  }
}

// ---------------------------------------------------------------------------
// Sliding-window flash attention. Grid (S/128, H), 512 threads = 8 waves.
// Wave w owns queries [qb0+16w, +16). 10 key tiles of 64 cover padded keys
// [qb0, qb0+640); each wave computes the 9 tiles intersecting its band.
// Fixed-max softmax (|s| <~ 8 << 88): p = exp(s/8); pad keys give p=1,
// matching reference zero-padding. P per-wave in LDS, XOR-swizzled.
// ---------------------------------------------------------------------------
__global__ __launch_bounds__(512, 4) void swa_fused(
    const u16* __restrict__ Qb, const u16* __restrict__ Kp,
    const u16* __restrict__ VTp, u16* __restrict__ o)
{
  __shared__ u16 Ks[64 * 64];       // (key, d), chunk-swizzled
  __shared__ u16 Vs[64 * 64];       // (d, key), chunk-swizzled
  __shared__ u16 Ps[8 * 16 * 64];   // per-wave (q, key), chunk-swizzled

  const int tid  = threadIdx.x;
  const int lane = tid & 63;
  const int w    = tid >> 6;
  const int quad = lane >> 4;
  const int c16  = lane & 15;
  const int h    = blockIdx.y;
  const int qb0  = blockIdx.x * 128;

  const long qrow = qb0 + w * 16 + c16;
  const bf16x8 aq0 = *(const bf16x8*)(&Qb[qrow * 1024 + h * 64 + quad * 8]);
  const bf16x8 aq1 = *(const bf16x8*)(&Qb[qrow * 1024 + h * 64 + 32 + quad * 8]);

  const int srow   = w * 8 + (lane >> 3);
  const int gchunk = (lane & 7) ^ (lane >> 3);
  const u16* gK = &Kp[((long)h * 4608 + qb0 + srow) * 64 + gchunk * 8];
  const u16* gV = &VTp[((long)h * 64 + srow) * 4608 + qb0 + gchunk * 8];
  u16* const lK = &Ks[(w * 8) * 64];
  u16* const lV = &Vs[(w * 8) * 64];

  const int rsw = c16 & 7;
  const u16* pK[4][2]; const u16* pV[4][2];
#pragma unroll
  for (int t16 = 0; t16 < 4; ++t16) {
    pK[t16][0] = &Ks[(t16 * 16 + c16) * 64 + (quad ^ rsw) * 8];
    pK[t16][1] = &Ks[(t16 * 16 + c16) * 64 + ((4 + quad) ^ rsw) * 8];
    pV[t16][0] = &Vs[(t16 * 16 + c16) * 64 + (quad ^ rsw) * 8];
    pV[t16][1] = &Vs[(t16 * 16 + c16) * 64 + ((4 + quad) ^ rsw) * 8];
  }
  u16* const Pw  = &Ps[w * 1024];
  const u16* pP0 = &Ps[w * 1024 + c16 * 64 + (quad ^ rsw) * 8];
  const u16* pP1 = &Ps[w * 1024 + c16 * 64 + ((4 + quad) ^ rsw) * 8];

  const int t_lo = w >> 2;
  const int t_hi = 8 + (w >> 2);
  const int dbase = c16 - 16 * w - quad * 4;

  f32x4 acc[4];
#pragma unroll
  for (int dt = 0; dt < 4; ++dt) acc[dt] = f32x4{0.f, 0.f, 0.f, 0.f};
  float rsum[4] = {0.f, 0.f, 0.f, 0.f};

  for (int t = 0; t < 10; ++t) {
    __syncthreads();
    gll16(gK, lK); gll16(gV, lV);
    gK += 64 * 64; gV += 64;
    __syncthreads();
    if (t < t_lo || t > t_hi) continue;

#pragma unroll
    for (int tcol = 0; tcol < 4; ++tcol) {
      const bf16x8 bk0 = *(const bf16x8*)pK[tcol][0];
      const bf16x8 bk1 = *(const bf16x8*)pK[tcol][1];
      f32x4 s = f32x4{0.f, 0.f, 0.f, 0.f};
      s = MFMA16(aq0, bk0, s);
      s = MFMA16(aq1, bk1, s);
#pragma unroll
      for (int r = 0; r < 4; ++r) {
        const int delta = dbase + t * 64 + tcol * 16 - r;
        const float p = ((u32)delta < 512u) ? __expf(s[r] * 0.125f) : 0.f;
        rsum[r] += p;
        const int q  = quad * 4 + r;
        const int kc = tcol * 16 + c16;
        Pw[q * 64 + (((kc >> 3) ^ (q & 7)) * 8) + (kc & 7)] = f2b(p);
      }
    }

    const bf16x8 ap0 = *(const bf16x8*)pP0;
    const bf16x8 ap1 = *(const bf16x8*)pP1;
#pragma unroll
    for (int dt = 0; dt < 4; ++dt) {
      const bf16x8 bv0 = *(const bf16x8*)pV[dt][0];
      const bf16x8 bv1 = *(const bf16x8*)pV[dt][1];
      acc[dt] = MFMA16(ap0, bv0, acc[dt]);
      acc[dt] = MFMA16(ap1, bv1, acc[dt]);
    }
  }

#pragma unroll
  for (int off = 1; off < 16; off <<= 1)
#pragma unroll
    for (int r = 0; r < 4; ++r)
      rsum[r] += __shfl_xor(rsum[r], off, 64);

  const int qp = qb0 + w * 16 + quad * 4;
#pragma unroll
  for (int r = 0; r < 4; ++r) {
    const float inv = 1.f / rsum[r];
#pragma unroll
    for (int dt = 0; dt < 4; ++dt)
      o[(long)(qp + r) * 1024 + h * 64 + dt * 16 + c16] = f2b(acc[dt][r] * inv);
  }
}

// ---------------------------------------------------------------------------
extern "C" void kernel_launch(void* const* d_in, const int* in_sizes, int n_in,
                              void* d_out, int out_size, void* d_ws, size_t ws_size,
                              hipStream_t stream)
{
  const float* x    = (const float*)d_in[0];   // (4096, 1024)
  const float* Wqkv = (const float*)d_in[1];   // (3072, 1024)
  const float* bqkv = (const float*)d_in[2];   // (3072,)
  const float* Wout = (const float*)d_in[3];   // (1024, 1024)
  const float* bout = (const float*)d_in[4];   // (1024,)
  float* out = (float*)d_out;                  // (4096, 1024)

  // ws layout (u16 elements): 52.4 MB total
  u16* xb    = (u16*)d_ws;                         // 4096*1024
  u16* wqkvb = xb    + (size_t)4096 * 1024;        // 3072*1024
  u16* woutb = wqkvb + (size_t)3072 * 1024;        // 1024*1024
  u16* Qb    = woutb + (size_t)1024 * 1024;        // 4096*1024
  u16* Kp    = Qb    + (size_t)4096 * 1024;        // 16*4608*64
  u16* VTp   = Kp    + (size_t)16 * 4608 * 64;     // 16*64*4608
  u16* Vb    = VTp   + (size_t)16 * 4608 * 64;     // 4096*1024 (o aliases)
  u16* o     = Vb;                                 // Vb dead after repack_v

  cvt_f32_bf16<<<4096 * 1024 / 8 / 256, 256, 0, stream>>>(x, xb, 4096 * 1024 / 8);
  cvt_f32_bf16<<<3072 * 1024 / 8 / 256, 256, 0, stream>>>(Wqkv, wqkvb, 3072 * 1024 / 8);
  cvt_f32_bf16<<<1024 * 1024 / 8 / 256, 256, 0, stream>>>(Wout, woutb, 1024 * 1024 / 8);

  gemm_qkv<<<dim3(3072 / 128, 4096 / 64), 256, 0, stream>>>(
      xb, wqkvb, bqkv, Qb, Kp, Vb);
  repack_v<<<dim3(72, 16), 256, 0, stream>>>(Vb, Kp, VTp);
  swa_fused<<<dim3(4096 / 128, 16), 512, 0, stream>>>(Qb, Kp, VTp, o);
  gemm_out<<<dim3(1024 / 64, 4096 / 64), 256, 0, stream>>>(o, woutb, bout, out);
}

// Round 6
// 166.998 us; speedup vs baseline: 1.0863x; 1.0863x over previous
//
#include <hip/hip_runtime.h>

// SlidingWindowAttention: B=1, S=4096, D=1024, H=16, d=64, WIN=512 (256 back / 255 fwd)
// Inputs/outputs FP32 storage (values bf16-rounded by harness).
//
// Pipeline:
//   0) cvt_f32_bf16 x3 : x, Wqkv, Wout -> bf16 (ws)
//   1) gemm_qkv        : qkv GEMM, 64x128 tile, BK=64 (16 MFMA/wave/barrier),
//                        scatters Q->Qb, K->Kp(pad), V->Vb
//   2) repack_v        : Vb -> VTp padded (h,d,key+256); zeroes Kp/VTp pads
//   3) swa_fused       : 64 queries/block (4 waves, 1024 blocks = 4/CU),
//                        9 key tiles, gll16 staging, fixed-max softmax -> o
//   4) gemm_out        : 64x64 tile, BK=64 -> fp32 out
//
// LDS swizzle (all kernels): row of 64 bf16 = 8 chunks of 8; element chunk c
// of row r lives in slot c ^ (r & 7). Row stride 128 B == 0 mod 32 banks, so
// bank depends only on slot -> both gll16 DMA writes (contiguous) and b128
// fragment reads (quad's lanes spread over all 8 slots) are conflict-free.

typedef __bf16 bf16x8 __attribute__((ext_vector_type(8)));
typedef float f32x4 __attribute__((ext_vector_type(4)));
typedef unsigned short u16;
typedef unsigned int u32;

#define MFMA16(a, b, c) __builtin_amdgcn_mfma_f32_16x16x32_bf16(a, b, c, 0, 0, 0)

__device__ __forceinline__ u16 f2b(float f) {   // RNE f32 -> bf16 bits
  union { float f; u32 u; } x; x.f = f;
  u32 r = x.u + 0x7fffu + ((x.u >> 16) & 1u);
  return (u16)(r >> 16);
}

union U8x16 { int4 v; u16 u[8]; };

// async 16B global -> LDS (dest = wave-uniform base + lane*16, HW-generated)
__device__ __forceinline__ void gll16(const u16* g, u16* l) {
  __builtin_amdgcn_global_load_lds(
      (const __attribute__((address_space(1))) u16*)g,
      (__attribute__((address_space(3))) u16*)l, 16, 0, 0);
}

// ---------------------------------------------------------------------------
__global__ void cvt_f32_bf16(const float* __restrict__ in, u16* __restrict__ out, int n8)
{
  const int i = blockIdx.x * blockDim.x + threadIdx.x;
  if (i >= n8) return;
  const float4 a = ((const float4*)in)[i * 2];
  const float4 b = ((const float4*)in)[i * 2 + 1];
  U8x16 t;
  t.u[0] = f2b(a.x); t.u[1] = f2b(a.y); t.u[2] = f2b(a.z); t.u[3] = f2b(a.w);
  t.u[4] = f2b(b.x); t.u[5] = f2b(b.y); t.u[6] = f2b(b.z); t.u[7] = f2b(b.w);
  ((int4*)out)[i] = t.v;
}

// ---------------------------------------------------------------------------
// QKV GEMM: 64x128 tile, BK=64, grid (24, 64) = 1536 blocks. 2x2 waves, each
// 32x64 output (2x4 MFMA tiles x 2 K-halves = 16 MFMA per barrier-round).
// Staging per wave per round: A 16 rows (2 gll16) + B 32 rows (4 gll16).
// Epilogue scatters: Q (n<1024) -> Qb; K -> Kp (h, key+256, d); V -> Vb.
// ---------------------------------------------------------------------------
__global__ __launch_bounds__(256, 4) void gemm_qkv(
    const u16* __restrict__ A, const u16* __restrict__ B,
    const float* __restrict__ bias,
    u16* __restrict__ Qb, u16* __restrict__ Kp, u16* __restrict__ Vb)
{
  __shared__ u16 As[64 * 64];    // 8 KB
  __shared__ u16 Bs[128 * 64];   // 16 KB

  const int K = 1024;
  const int tid  = threadIdx.x;
  const int lane = tid & 63;
  const int wave = tid >> 6;
  const int quad = lane >> 4;
  const int c16  = lane & 15;
  const int wr   = wave >> 1;            // M half (32 rows)
  const int wc   = wave & 1;             // N half (64 cols)
  const long m0 = (long)blockIdx.y * 64;
  const long n0 = (long)blockIdx.x * 128;

  // staging lane map: lane i -> row grp+(i>>3), slot i&7, global chunk
  // (i&7)^((i>>3)&7). One gll16 = 8 rows x 8 slots = 1 KB.
  const int rowo   = lane >> 3;
  const int schunk = (lane & 7) ^ rowo;
  const u16* gA0 = &A[(m0 + wave * 16 + rowo) * K + schunk * 8];
  const u16* gA1 = gA0 + 8 * K;
  const u16* gB0 = &B[(n0 + wave * 32 + rowo) * K + schunk * 8];
  const u16* gB1 = gB0 + 8 * K;
  const u16* gB2 = gB0 + 16 * K;
  const u16* gB3 = gB0 + 24 * K;
  u16* const lA0 = &As[(wave * 16) * 64];
  u16* const lA1 = lA0 + 8 * 64;
  u16* const lB0 = &Bs[(wave * 32) * 64];
  u16* const lB1 = lB0 + 8 * 64;
  u16* const lB2 = lB0 + 16 * 64;
  u16* const lB3 = lB0 + 24 * 64;

  // fragment pointers: row tile*16+c16, chunks {quad, quad+4}, slot = chunk^(row&7)
  const int rsw = c16 & 7;
  const u16* pa[2][2]; const u16* pb[4][2];
#pragma unroll
  for (int i = 0; i < 2; ++i) {
    pa[i][0] = &As[(wr * 32 + i * 16 + c16) * 64 + (quad ^ rsw) * 8];
    pa[i][1] = &As[(wr * 32 + i * 16 + c16) * 64 + ((4 + quad) ^ rsw) * 8];
  }
#pragma unroll
  for (int j = 0; j < 4; ++j) {
    pb[j][0] = &Bs[(wc * 64 + j * 16 + c16) * 64 + (quad ^ rsw) * 8];
    pb[j][1] = &Bs[(wc * 64 + j * 16 + c16) * 64 + ((4 + quad) ^ rsw) * 8];
  }

  f32x4 acc[2][4];
#pragma unroll
  for (int i = 0; i < 2; ++i)
#pragma unroll
    for (int j = 0; j < 4; ++j)
      acc[i][j] = f32x4{0.f, 0.f, 0.f, 0.f};

  for (int k0 = 0; k0 < K; k0 += 64) {
    __syncthreads();
    gll16(gA0, lA0); gll16(gA1, lA1);
    gll16(gB0, lB0); gll16(gB1, lB1); gll16(gB2, lB2); gll16(gB3, lB3);
    gA0 += 64; gA1 += 64; gB0 += 64; gB1 += 64; gB2 += 64; gB3 += 64;
    __syncthreads();

#pragma unroll
    for (int h = 0; h < 2; ++h) {
      bf16x8 af[2], bfr[4];
#pragma unroll
      for (int i = 0; i < 2; ++i) af[i]  = *(const bf16x8*)pa[i][h];
#pragma unroll
      for (int j = 0; j < 4; ++j) bfr[j] = *(const bf16x8*)pb[j][h];
#pragma unroll
      for (int i = 0; i < 2; ++i)
#pragma unroll
        for (int j = 0; j < 4; ++j)
          acc[i][j] = MFMA16(af[i], bfr[j], acc[i][j]);
    }
  }

  const int region = (int)(n0 >> 10);      // 0=Q, 1=K, 2=V (block-uniform)
#pragma unroll
  for (int i = 0; i < 2; ++i) {
    const long row0 = m0 + wr * 32 + i * 16 + quad * 4;
#pragma unroll
    for (int j = 0; j < 4; ++j) {
      const long col = n0 + wc * 64 + j * 16 + c16;
      const float bv = bias[col];
#pragma unroll
      for (int r = 0; r < 4; ++r) {
        const u16 v = f2b(acc[i][j][r] + bv);
        const long row = row0 + r;
        if (region == 0) {
          Qb[row * 1024 + col] = v;
        } else if (region == 1) {
          const int n1 = (int)(col - 1024);
          const int h = n1 >> 6, d = n1 & 63;
          Kp[((long)h * 4608 + row + 256) * 64 + d] = v;
        } else {
          Vb[row * 1024 + (col - 2048)] = v;
        }
      }
    }
  }
}

// ---------------------------------------------------------------------------
// Output GEMM: 64x64 tile, BK=64, grid (16, 64) = 1024 blocks = 4/CU.
// 2x2 waves, each 32x32 (2x2 MFMA tiles x 2 K-halves = 8 MFMA/round). fp32 out.
// ---------------------------------------------------------------------------
__global__ __launch_bounds__(256, 4) void gemm_out(
    const u16* __restrict__ A, const u16* __restrict__ B,
    const float* __restrict__ bias, float* __restrict__ C)
{
  __shared__ u16 As[64 * 64];    // 8 KB
  __shared__ u16 Bs[64 * 64];    // 8 KB

  const int K = 1024, N = 1024;
  const int tid  = threadIdx.x;
  const int lane = tid & 63;
  const int wave = tid >> 6;
  const int quad = lane >> 4;
  const int c16  = lane & 15;
  const int wr   = wave >> 1;
  const int wc   = wave & 1;
  const long m0 = (long)blockIdx.y * 64;
  const long n0 = (long)blockIdx.x * 64;

  const int rowo   = lane >> 3;
  const int schunk = (lane & 7) ^ rowo;
  const u16* gA0 = &A[(m0 + wave * 16 + rowo) * K + schunk * 8];
  const u16* gA1 = gA0 + 8 * K;
  const u16* gB0 = &B[(n0 + wave * 16 + rowo) * K + schunk * 8];
  const u16* gB1 = gB0 + 8 * K;
  u16* const lA0 = &As[(wave * 16) * 64];
  u16* const lA1 = lA0 + 8 * 64;
  u16* const lB0 = &Bs[(wave * 16) * 64];
  u16* const lB1 = lB0 + 8 * 64;

  const int rsw = c16 & 7;
  const u16* pa[2][2]; const u16* pb[2][2];
#pragma unroll
  for (int i = 0; i < 2; ++i) {
    pa[i][0] = &As[(wr * 32 + i * 16 + c16) * 64 + (quad ^ rsw) * 8];
    pa[i][1] = &As[(wr * 32 + i * 16 + c16) * 64 + ((4 + quad) ^ rsw) * 8];
    pb[i][0] = &Bs[(wc * 32 + i * 16 + c16) * 64 + (quad ^ rsw) * 8];
    pb[i][1] = &Bs[(wc * 32 + i * 16 + c16) * 64 + ((4 + quad) ^ rsw) * 8];
  }

  f32x4 acc[2][2];
#pragma unroll
  for (int i = 0; i < 2; ++i)
#pragma unroll
    for (int j = 0; j < 2; ++j)
      acc[i][j] = f32x4{0.f, 0.f, 0.f, 0.f};

  for (int k0 = 0; k0 < K; k0 += 64) {
    __syncthreads();
    gll16(gA0, lA0); gll16(gA1, lA1);
    gll16(gB0, lB0); gll16(gB1, lB1);
    gA0 += 64; gA1 += 64; gB0 += 64; gB1 += 64;
    __syncthreads();

#pragma unroll
    for (int h = 0; h < 2; ++h) {
      bf16x8 af[2], bfr[2];
#pragma unroll
      for (int i = 0; i < 2; ++i) af[i]  = *(const bf16x8*)pa[i][h];
#pragma unroll
      for (int j = 0; j < 2; ++j) bfr[j] = *(const bf16x8*)pb[j][h];
#pragma unroll
      for (int i = 0; i < 2; ++i)
#pragma unroll
        for (int j = 0; j < 2; ++j)
          acc[i][j] = MFMA16(af[i], bfr[j], acc[i][j]);
    }
  }

#pragma unroll
  for (int i = 0; i < 2; ++i) {
    const long row0 = m0 + wr * 32 + i * 16 + quad * 4;
#pragma unroll
    for (int j = 0; j < 2; ++j) {
      const long col = n0 + wc * 32 + j * 16 + c16;
      const float bv = bias[col];
#pragma unroll
      for (int r = 0; r < 4; ++r)
        C[(row0 + r) * N + col] = acc[i][j][r] + bv;
    }
  }
}

// ---------------------------------------------------------------------------
// V repack: Vb(S,D) -> VTp(h, d, key+256) transposed; zeroes pad tiles of
// both Kp and VTp. Grid (72 padded key tiles, 16 heads), 256 threads.
// Dual-XOR swizzled LDS transpose -> both write and read conflict-free.
// ---------------------------------------------------------------------------
__global__ __launch_bounds__(256, 2) void repack_v(
    const u16* __restrict__ Vb, u16* __restrict__ Kp, u16* __restrict__ VTp)
{
  __shared__ u16 lds[64 * 64];
  const int tile = blockIdx.x;          // padded key tile, 0..71
  const int h    = blockIdx.y;
  const int tid  = threadIdx.x;
  const int kt   = tile * 64 - 256;     // actual key start
  const long vtb = (long)h * 64 * 4608;

  if (kt < 0 || kt >= 4096) {           // pad tile: zero Kp rows + VTp cols
    const int4 z = {0, 0, 0, 0};
    for (int idx = tid; idx < 512; idx += 256) {
      const int r = idx >> 3, c = idx & 7;
      *(int4*)(&Kp[((long)h * 4608 + tile * 64 + r) * 64 + c * 8]) = z;
      *(int4*)(&VTp[vtb + (long)r * 4608 + tile * 64 + c * 8])     = z;
    }
    return;
  }

  for (int idx = tid; idx < 512; idx += 256) {
    const int r = idx >> 3, c = idx & 7;            // key r, d-chunk c
    U8x16 t; t.v = *(const int4*)(&Vb[(long)(kt + r) * 1024 + h * 64 + c * 8]);
#pragma unroll
    for (int j = 0; j < 8; ++j) {
      const int d = c * 8 + j;
      lds[d * 64 + (((r >> 3) ^ ((c + j) & 7)) * 8) + (r & 7)] = t.u[j];
    }
  }
  __syncthreads();
  for (int idx = tid; idx < 512; idx += 256) {
    const int d = idx >> 3, c2 = idx & 7;           // d row, key-chunk c2
    const int sl = (c2 ^ ((d + (d >> 3)) & 7)) * 8;
    const int4 v = *(const int4*)(&lds[d * 64 + sl]);
    *(int4*)(&VTp[vtb + (long)d * 4608 + 256 + kt + c2 * 8]) = v;
  }
}

// ---------------------------------------------------------------------------
// Sliding-window flash attention. Grid (S/64, H) = 1024 blocks, 256 thr =
// 4 waves (4 blocks/CU). Wave w owns queries [qb0+16w, +16). 9 key tiles of
// 64 cover padded keys [qb0, qb0+576) = actual [qb0-256, qb0+320); every
// wave's band intersects all 9 tiles -> no skip.
// Fixed-max softmax (|s| <~ 8 << 88): p = exp(s/8); pad keys (k=0,v=0) give
// p=1 in the denominator, matching reference zero-padding exactly.
// P per-wave in LDS (C-layout -> A-layout), slot-swizzled.
// ---------------------------------------------------------------------------
__global__ __launch_bounds__(256, 4) void swa_fused(
    const u16* __restrict__ Qb, const u16* __restrict__ Kp,
    const u16* __restrict__ VTp, u16* __restrict__ o)
{
  __shared__ u16 Ks[64 * 64];       // (key, d), slot-swizzled
  __shared__ u16 Vs[64 * 64];       // (d, key), slot-swizzled
  __shared__ u16 Ps[4 * 16 * 64];   // per-wave (q, key), slot-swizzled

  const int tid  = threadIdx.x;
  const int lane = tid & 63;
  const int w    = tid >> 6;
  const int quad = lane >> 4;
  const int c16  = lane & 15;
  const int h    = blockIdx.y;
  const int qb0  = blockIdx.x * 64;

  const long qrow = qb0 + w * 16 + c16;
  const bf16x8 aq0 = *(const bf16x8*)(&Qb[qrow * 1024 + h * 64 + quad * 8]);
  const bf16x8 aq1 = *(const bf16x8*)(&Qb[qrow * 1024 + h * 64 + 32 + quad * 8]);

  // staging: wave w covers rows [w*16, +16) of Ks (keys) and Vs (d), 2 gll16 each
  const int rowo   = lane >> 3;
  const int gchunk = (lane & 7) ^ rowo;
  const u16* gK0 = &Kp[((long)h * 4608 + qb0 + w * 16 + rowo) * 64 + gchunk * 8];
  const u16* gK1 = gK0 + 8 * 64;
  const u16* gV0 = &VTp[((long)h * 64 + w * 16 + rowo) * 4608 + qb0 + gchunk * 8];
  const u16* gV1 = gV0 + 8 * 4608;
  u16* const lK0 = &Ks[(w * 16) * 64];
  u16* const lK1 = lK0 + 8 * 64;
  u16* const lV0 = &Vs[(w * 16) * 64];
  u16* const lV1 = lV0 + 8 * 64;

  const int rsw = c16 & 7;
  const u16* pK[4][2]; const u16* pV[4][2];
#pragma unroll
  for (int t16 = 0; t16 < 4; ++t16) {
    pK[t16][0] = &Ks[(t16 * 16 + c16) * 64 + (quad ^ rsw) * 8];
    pK[t16][1] = &Ks[(t16 * 16 + c16) * 64 + ((4 + quad) ^ rsw) * 8];
    pV[t16][0] = &Vs[(t16 * 16 + c16) * 64 + (quad ^ rsw) * 8];
    pV[t16][1] = &Vs[(t16 * 16 + c16) * 64 + ((4 + quad) ^ rsw) * 8];
  }
  u16* const Pw  = &Ps[w * 1024];
  const u16* pP0 = &Ps[w * 1024 + c16 * 64 + (quad ^ rsw) * 8];
  const u16* pP1 = &Ps[w * 1024 + c16 * 64 + ((4 + quad) ^ rsw) * 8];

  const int dbase = c16 - 16 * w - quad * 4;   // delta = dbase + t*64 + tcol*16 - r

  f32x4 acc[4];
#pragma unroll
  for (int dt = 0; dt < 4; ++dt) acc[dt] = f32x4{0.f, 0.f, 0.f, 0.f};
  float rsum[4] = {0.f, 0.f, 0.f, 0.f};

  for (int t = 0; t < 9; ++t) {
    __syncthreads();
    gll16(gK0, lK0); gll16(gK1, lK1);
    gll16(gV0, lV0); gll16(gV1, lV1);
    gK0 += 64 * 64; gK1 += 64 * 64; gV0 += 64; gV1 += 64;
    __syncthreads();

#pragma unroll
    for (int tcol = 0; tcol < 4; ++tcol) {
      const bf16x8 bk0 = *(const bf16x8*)pK[tcol][0];
      const bf16x8 bk1 = *(const bf16x8*)pK[tcol][1];
      f32x4 s = f32x4{0.f, 0.f, 0.f, 0.f};
      s = MFMA16(aq0, bk0, s);
      s = MFMA16(aq1, bk1, s);
#pragma unroll
      for (int r = 0; r < 4; ++r) {
        const int delta = dbase + t * 64 + tcol * 16 - r;
        const float p = ((u32)delta < 512u) ? __expf(s[r] * 0.125f) : 0.f;
        rsum[r] += p;
        const int q  = quad * 4 + r;
        const int kc = tcol * 16 + c16;
        Pw[q * 64 + (((kc >> 3) ^ (q & 7)) * 8) + (kc & 7)] = f2b(p);
      }
    }

    const bf16x8 ap0 = *(const bf16x8*)pP0;
    const bf16x8 ap1 = *(const bf16x8*)pP1;
#pragma unroll
    for (int dt = 0; dt < 4; ++dt) {
      const bf16x8 bv0 = *(const bf16x8*)pV[dt][0];
      const bf16x8 bv1 = *(const bf16x8*)pV[dt][1];
      acc[dt] = MFMA16(ap0, bv0, acc[dt]);
      acc[dt] = MFMA16(ap1, bv1, acc[dt]);
    }
  }

#pragma unroll
  for (int off = 1; off < 16; off <<= 1)
#pragma unroll
    for (int r = 0; r < 4; ++r)
      rsum[r] += __shfl_xor(rsum[r], off, 64);

  const int qp = qb0 + w * 16 + quad * 4;
#pragma unroll
  for (int r = 0; r < 4; ++r) {
    const float inv = 1.f / rsum[r];
#pragma unroll
    for (int dt = 0; dt < 4; ++dt)
      o[(long)(qp + r) * 1024 + h * 64 + dt * 16 + c16] = f2b(acc[dt][r] * inv);
  }
}

// ---------------------------------------------------------------------------
extern "C" void kernel_launch(void* const* d_in, const int* in_sizes, int n_in,
                              void* d_out, int out_size, void* d_ws, size_t ws_size,
                              hipStream_t stream)
{
  const float* x    = (const float*)d_in[0];   // (4096, 1024)
  const float* Wqkv = (const float*)d_in[1];   // (3072, 1024)
  const float* bqkv = (const float*)d_in[2];   // (3072,)
  const float* Wout = (const float*)d_in[3];   // (1024, 1024)
  const float* bout = (const float*)d_in[4];   // (1024,)
  float* out = (float*)d_out;                  // (4096, 1024)

  // ws layout (u16 elements): 52.4 MB total
  u16* xb    = (u16*)d_ws;                         // 4096*1024
  u16* wqkvb = xb    + (size_t)4096 * 1024;        // 3072*1024
  u16* woutb = wqkvb + (size_t)3072 * 1024;        // 1024*1024
  u16* Qb    = woutb + (size_t)1024 * 1024;        // 4096*1024
  u16* Kp    = Qb    + (size_t)4096 * 1024;        // 16*4608*64
  u16* VTp   = Kp    + (size_t)16 * 4608 * 64;     // 16*64*4608
  u16* Vb    = VTp   + (size_t)16 * 4608 * 64;     // 4096*1024 (o aliases)
  u16* o     = Vb;                                 // Vb dead after repack_v

  cvt_f32_bf16<<<4096 * 1024 / 8 / 256, 256, 0, stream>>>(x, xb, 4096 * 1024 / 8);
  cvt_f32_bf16<<<3072 * 1024 / 8 / 256, 256, 0, stream>>>(Wqkv, wqkvb, 3072 * 1024 / 8);
  cvt_f32_bf16<<<1024 * 1024 / 8 / 256, 256, 0, stream>>>(Wout, woutb, 1024 * 1024 / 8);

  gemm_qkv<<<dim3(3072 / 128, 4096 / 64), 256, 0, stream>>>(
      xb, wqkvb, bqkv, Qb, Kp, Vb);
  repack_v<<<dim3(72, 16), 256, 0, stream>>>(Vb, Kp, VTp);
  swa_fused<<<dim3(4096 / 64, 16), 256, 0, stream>>>(Qb, Kp, VTp, o);
  gemm_out<<<dim3(1024 / 64, 4096 / 64), 256, 0, stream>>>(o, woutb, bout, out);
}